// Round 6
// baseline (154.099 us; speedup 1.0000x reference)
//
#include <hip/hip_runtime.h>
#include <hip/hip_bf16.h>

typedef __attribute__((ext_vector_type(8))) short short8;
typedef __attribute__((ext_vector_type(4))) float f32x4;

// ---------------- helpers ----------------
__device__ __forceinline__ ushort f2b(float f) {
    __hip_bfloat16 h = __float2bfloat16(f);
    return *reinterpret_cast<ushort*>(&h);
}
__device__ __forceinline__ float b2f(ushort u) {
    return __uint_as_float(((unsigned)u) << 16);
}
__device__ __forceinline__ void gload16(const ushort* g, ushort* l) {
    __builtin_amdgcn_global_load_lds(
        (const __attribute__((address_space(1))) void*)g,
        (__attribute__((address_space(3))) void*)l, 16, 0, 0);
}

// ============================================================================
// QKV: 256x256-tile NT GEMM, BK=32, 4-slot LDS ring, counted vmcnt,
// ONE barrier per K-tile. 512 thr = 8 waves (2M x 4N), per-wave 128x64 out
// (acc[8][4]) -> 12 ds_read_b128 feed 32 MFMA (43.7 FLOP/LDS-byte).
// LDS: 4 slots x (A 16KB + B 16KB) = 128 KB -> 1 block/CU.
// Same 16-row-subtile XOR-swizzle layout as r4/r5 (0 bank conflicts),
// pre-swizzled global source for global_load_lds (both-sides).
// Grid 384 = 8*48 XCD-bijective. N=3072 concat; V written transposed.
// ============================================================================
__global__ __launch_bounds__(512, 1) void qkv_gemm256(
    const ushort* __restrict__ xb, const ushort* __restrict__ Wcat,
    const float* __restrict__ bk, const float* __restrict__ bq, const float* __restrict__ bv,
    ushort* __restrict__ Kb, ushort* __restrict__ Qb, ushort* __restrict__ Vt) {
    constexpr int T = 2048, C = 1024, K = 1024, NT = 32;
    __shared__ ushort smem[65536];  // 128 KB

    const int tid = threadIdx.x;
    const int l = tid & 63, w = tid >> 6;
    const int wm = (w >> 2) * 128, wn = (w & 3) * 64;
    const int lr = l & 15, lk = l >> 4;

    const int b = blockIdx.x;                 // 384 = 8*48
    const int wg = (b & 7) * 48 + (b >> 3);   // XCD-bijective
    const int m0 = (wg / 12) * 256, n0 = (wg % 12) * 256;

    // staging coords (pre-swizzled source; linear LDS dest)
    const int srow = w * 16 + (l >> 2);                      // 0..127
    const int scb = ((l & 3) << 4) ^ ((l & 32) ? 32 : 0);    // swizzled byte col
    const ushort* gA = xb + (size_t)(m0 + srow) * K + (scb >> 1);
    const ushort* gB = Wcat + (size_t)(n0 + srow) * K + (scb >> 1);

    // ds_read per-lane base (ushort units), swizzled
    const int LB = lr * 32 + ((lk << 3) ^ ((lr >= 8) ? 16 : 0));
    // per-wave ds_read unit bases within a slot
    const int Abase = (wm >> 7) * 4096;                          // A unit 0/1
    const int Bbase = 8192 + ((wn >> 7) * 4096) + ((wn & 64) >> 4) * 512;

    f32x4 acc[8][4] = {};

    // slot s at s*16384 ushort: A rows 0-127 at +0, rows 128-255 at +4096,
    // B rows 0-127 at +8192, rows 128-255 at +12288. 4 gloads/thread/tile.
#define STAGEQ(tt)                                                        \
    {                                                                     \
        const int _ko = (tt) * 32;                                        \
        ushort* _s = smem + ((tt) & 3) * 16384 + w * 512;                 \
        gload16(gA + _ko,                  _s);                           \
        gload16(gA + (size_t)128 * K + _ko, _s + 4096);                   \
        gload16(gB + _ko,                  _s + 8192);                    \
        gload16(gB + (size_t)128 * K + _ko, _s + 12288);                  \
    }

    STAGEQ(0); STAGEQ(1); STAGEQ(2);

    for (int u = 0; u < NT; ++u) {
        const int rem = NT - 1 - u;
        if (rem >= 2)      asm volatile("s_waitcnt vmcnt(8)" ::: "memory");
        else if (rem == 1) asm volatile("s_waitcnt vmcnt(4)" ::: "memory");
        else               asm volatile("s_waitcnt vmcnt(0)" ::: "memory");
        __builtin_amdgcn_s_barrier();
        asm volatile("" ::: "memory");

        const ushort* slot = smem + (u & 3) * 16384;
        const ushort* Ab = slot + Abase + LB;
        const ushort* Bb = slot + Bbase + LB;
        short8 af[8], bfr[4];
#pragma unroll
        for (int f = 0; f < 8; ++f) af[f] = *reinterpret_cast<const short8*>(Ab + f * 512);
#pragma unroll
        for (int g = 0; g < 4; ++g) bfr[g] = *reinterpret_cast<const short8*>(Bb + g * 512);

        if (u + 3 < NT) STAGEQ(u + 3);

        __builtin_amdgcn_s_setprio(1);
#pragma unroll
        for (int f = 0; f < 8; ++f)
#pragma unroll
            for (int g = 0; g < 4; ++g)
                acc[f][g] = __builtin_amdgcn_mfma_f32_16x16x32_bf16(af[f], bfr[g], acc[f][g], 0, 0, 0);
        __builtin_amdgcn_s_setprio(0);
    }
#undef STAGEQ

    // ---- epilogue: D col = lane&15, row = (lane>>4)*4 + reg ----
    const int zsel = n0 >> 10;
    const int c0 = (n0 & 1023) + wn;
    if (zsel < 2) {
        ushort* O = (zsel == 0) ? Kb : Qb;
        const float* bias = (zsel == 0) ? bk : bq;
#pragma unroll
        for (int f = 0; f < 8; ++f)
#pragma unroll
            for (int g = 0; g < 4; ++g) {
                const int gc = c0 + g * 16 + lr;
                const float badd = bias[gc];
#pragma unroll
                for (int rr = 0; rr < 4; ++rr) {
                    const int gr = m0 + wm + f * 16 + lk * 4 + rr;
                    O[(size_t)gr * C + gc] = f2b(acc[f][g][rr] + badd);
                }
            }
    } else {
        const int zb = (m0 + wm) >> 11;
        const int s0 = (m0 + wm) & 2047;
        ushort* Vz = Vt + (size_t)zb * C * T;
#pragma unroll
        for (int f = 0; f < 8; ++f)
#pragma unroll
            for (int g = 0; g < 4; ++g) {
                const int gc = c0 + g * 16 + lr;
                const float badd = bv[gc];
                const int s = s0 + f * 16 + lk * 4;
                ushort tmp[4];
#pragma unroll
                for (int rr = 0; rr < 4; ++rr) tmp[rr] = f2b(acc[f][g][rr] + badd);
                *reinterpret_cast<uint2*>(Vz + (size_t)gc * T + s) =
                    *reinterpret_cast<uint2*>(tmp);
            }
    }
}

// ============================================================================
// 3-slot ring 128x128 NT GEMM (unchanged, proven) for scores / PV.
// ============================================================================
template <int MODE>
__global__ __launch_bounds__(256, 3) void gemm_ring(
    const ushort* __restrict__ Kb, const ushort* __restrict__ Qb,
    const ushort* __restrict__ Vt, ushort* __restrict__ Sb, float* __restrict__ out) {
    constexpr int T = 2048, C = 1024;
    __shared__ ushort smem[24576];  // 48 KB

    const int tid = threadIdx.x;
    const int l = tid & 63, w = tid >> 6;
    const int wm = (w >> 1) * 64, wn = (w & 1) * 64;
    const int lr = l & 15, lk = l >> 4;

    int m0, n0, nt, iblk = 0, jblk = 0, z = 0;
    const ushort *Au, *Bu;
    int ldA, ldB;
    if constexpr (MODE == 1) {
        const int wg0 = blockIdx.x;                  // 544 = 8*68
        const int wg = (wg0 & 7) * 68 + (wg0 >> 3);
        z = wg / 136; const int t136 = wg % 136;
        int i = (int)((sqrtf(8.f * t136 + 1.f) - 1.f) * 0.5f);
        while ((i + 1) * (i + 2) / 2 <= t136) ++i;
        while (i * (i + 1) / 2 > t136) --i;
        const int j = t136 - i * (i + 1) / 2;
        iblk = i; jblk = j;
        m0 = i * 128; n0 = j * 128;
        Au = Qb + (size_t)z * T * C + (size_t)m0 * C; ldA = C;
        Bu = Kb + (size_t)z * T * C + (size_t)n0 * C; ldB = C;
        nt = 32;
    } else {
        const int wg0 = blockIdx.x;                  // 512 = 8*64
        const int wg = (wg0 & 7) * 64 + (wg0 >> 3);
        const int half = wg >> 8, s2 = wg & 255;
        z = s2 >> 6; const int r6 = s2 & 63;
        const int nb = r6 & 7, ii = r6 >> 3;
        const int i = half ? (15 - ii) : ii;
        iblk = i;
        m0 = i * 128; n0 = nb * 128;
        Au = Sb + (size_t)z * T * T + (size_t)m0 * T; ldA = T;
        Bu = Vt + (size_t)z * C * T + (size_t)n0 * T; ldB = T;
        nt = 4 * (i + 1);
    }

    const int srow = w * 16 + (l >> 2);
    const int scb = ((l & 3) << 4) ^ ((l >= 32) ? 32 : 0);
    const ushort* gA = Au + (size_t)srow * ldA + (scb >> 1);
    const ushort* gB = Bu + (size_t)srow * ldB + (scb >> 1);
    const size_t a64 = (size_t)64 * ldA, b64 = (size_t)64 * ldB;
    const int LBu = lr * 32 + ((lk << 3) ^ ((lr >= 8) ? 16 : 0));

    f32x4 acc[4][4] = {};

#define STAGE(tt, sl)                                                    \
    {                                                                    \
        const int _ko = (tt) * 32;                                       \
        ushort* _d = smem + (sl) * 8192 + w * 512;                       \
        gload16(gA + _ko,        _d);                                    \
        gload16(gA + a64 + _ko,  _d + 2048);                             \
        gload16(gB + _ko,        _d + 4096);                             \
        gload16(gB + b64 + _ko,  _d + 6144);                             \
    }

    STAGE(0, 0);
    STAGE(1, 1);
    asm volatile("s_waitcnt vmcnt(4)" ::: "memory");
    __builtin_amdgcn_s_barrier();
    asm volatile("" ::: "memory");

    int sc = 0, ss = 2;
    for (int t = 0; t < nt; ++t) {
        const ushort* As = smem + sc * 8192 + (wm >> 4) * 512 + LBu;
        const ushort* Bs = smem + sc * 8192 + 4096 + (wn >> 4) * 512 + LBu;
        short8 af[4], bf[4];
#pragma unroll
        for (int q = 0; q < 4; ++q) {
            af[q] = *reinterpret_cast<const short8*>(As + q * 512);
            bf[q] = *reinterpret_cast<const short8*>(Bs + q * 512);
        }
        if (t + 2 < nt) STAGE(t + 2, ss);
        __builtin_amdgcn_s_setprio(1);
#pragma unroll
        for (int mf = 0; mf < 4; ++mf)
#pragma unroll
            for (int nf = 0; nf < 4; ++nf)
                acc[mf][nf] = __builtin_amdgcn_mfma_f32_16x16x32_bf16(af[mf], bf[nf], acc[mf][nf], 0, 0, 0);
        __builtin_amdgcn_s_setprio(0);
        if (t + 1 < nt) {
            if (t + 2 < nt) asm volatile("s_waitcnt vmcnt(4)" ::: "memory");
            else            asm volatile("s_waitcnt vmcnt(0)" ::: "memory");
            __builtin_amdgcn_s_barrier();
            asm volatile("" ::: "memory");
        }
        sc = (sc == 2) ? 0 : sc + 1;
        ss = (ss == 2) ? 0 : ss + 1;
    }
#undef STAGE

    if constexpr (MODE == 1) {
        ushort* Sp = Sb + (size_t)z * T * T;
        const bool diag = (iblk == jblk);
#pragma unroll
        for (int mf = 0; mf < 4; ++mf)
#pragma unroll
            for (int nf = 0; nf < 4; ++nf) {
                const int gc = n0 + wn + nf * 16 + lr;
#pragma unroll
                for (int rr = 0; rr < 4; ++rr) {
                    const int gr = m0 + wm + mf * 16 + lk * 4 + rr;
                    if (!diag || gc <= gr)
                        Sp[(size_t)gr * T + gc] = f2b(acc[mf][nf][rr] * 0.03125f);
                }
            }
    } else {
        float* Op = out + (size_t)z * T * C;
#pragma unroll
        for (int mf = 0; mf < 4; ++mf)
#pragma unroll
            for (int nf = 0; nf < 4; ++nf) {
                const int gc = n0 + wn + nf * 16 + lr;
#pragma unroll
                for (int rr = 0; rr < 4; ++rr) {
                    const int gr = m0 + wm + mf * 16 + lk * 4 + rr;
                    Op[(size_t)gr * C + gc] = acc[mf][nf][rr];
                }
            }
    }
}

// ---- fused fp32 -> bf16 convert for x, Wk, Wq, Wv ----
__global__ __launch_bounds__(256) void cvt_all(
    const float* __restrict__ x, const float* __restrict__ Wk,
    const float* __restrict__ Wq, const float* __restrict__ Wv,
    ushort* __restrict__ xb, ushort* __restrict__ Wcat) {
    constexpr int C = 1024;
    constexpr int NX = 8388608 / 8, NW = C * C / 8;
    int i = blockIdx.x * 256 + threadIdx.x;
    const float* src; ushort* dst;
    if (i < NX)               { src = x;  dst = xb; }
    else if (i < NX + NW)     { src = Wk; dst = Wcat;                 i -= NX; }
    else if (i < NX + 2 * NW) { src = Wq; dst = Wcat + (size_t)C * C; i -= NX + NW; }
    else                      { src = Wv; dst = Wcat + 2 * (size_t)C * C; i -= NX + 2 * NW; }
    const float4* p = reinterpret_cast<const float4*>(src) + (size_t)i * 2;
    float4 a = p[0], b = p[1];
    ushort o[8] = {f2b(a.x), f2b(a.y), f2b(a.z), f2b(a.w),
                   f2b(b.x), f2b(b.y), f2b(b.z), f2b(b.w)};
    reinterpret_cast<uint4*>(dst)[i] = *reinterpret_cast<uint4*>(o);
}

// ---- causal-aware row softmax ----
__global__ __launch_bounds__(256) void softmax_rows(ushort* __restrict__ S, int T) {
    const int g = blockIdx.x;
    const int r = g & (T - 1);
    ushort* p = S + (size_t)g * T;
    const int tid = threadIdx.x;
    const int lane = tid & 63, wave = tid >> 6;
    const int c0 = tid * 8;
    const int n_write = ((r >> 7) + 1) << 7;

    float f[8];
    if (c0 <= r) {
        uint4 raw = *reinterpret_cast<const uint4*>(p + c0);
        ushort* rs = reinterpret_cast<ushort*>(&raw);
#pragma unroll
        for (int j = 0; j < 8; ++j) f[j] = (c0 + j <= r) ? b2f(rs[j]) : -INFINITY;
    } else {
#pragma unroll
        for (int j = 0; j < 8; ++j) f[j] = -INFINITY;
    }

    float mx = f[0];
#pragma unroll
    for (int j = 1; j < 8; ++j) mx = fmaxf(mx, f[j]);
#pragma unroll
    for (int o = 32; o > 0; o >>= 1) mx = fmaxf(mx, __shfl_xor(mx, o));

    __shared__ float redm[4], reds[4];
    if (lane == 0) redm[wave] = mx;
    __syncthreads();
    mx = fmaxf(fmaxf(redm[0], redm[1]), fmaxf(redm[2], redm[3]));

    float e[8], s = 0.f;
#pragma unroll
    for (int j = 0; j < 8; ++j) { e[j] = __expf(f[j] - mx); s += e[j]; }
#pragma unroll
    for (int o = 32; o > 0; o >>= 1) s += __shfl_xor(s, o);
    if (lane == 0) reds[wave] = s;
    __syncthreads();
    s = reds[0] + reds[1] + reds[2] + reds[3];

    const float inv = 1.f / s;
    if (c0 < n_write) {
        ushort outv[8];
#pragma unroll
        for (int j = 0; j < 8; ++j) outv[j] = f2b(e[j] * inv);
        *reinterpret_cast<uint4*>(p + c0) = *reinterpret_cast<uint4*>(outv);
    }
}

extern "C" void kernel_launch(void* const* d_in, const int* in_sizes, int n_in,
                              void* d_out, int out_size, void* d_ws, size_t ws_size,
                              hipStream_t stream) {
    const float* x  = (const float*)d_in[0];
    const float* Wk = (const float*)d_in[1];
    const float* bk = (const float*)d_in[2];
    const float* Wq = (const float*)d_in[3];
    const float* bq = (const float*)d_in[4];
    const float* Wv = (const float*)d_in[5];
    const float* bv = (const float*)d_in[6];
    float* out = (float*)d_out;

    constexpr int B = 4, T = 2048, C = 1024;
    constexpr size_t BTC = (size_t)B * T * C;  // 8388608

    ushort* Kb = (ushort*)d_ws;
    ushort* Qb = Kb + BTC;
    ushort* Vt = Qb + BTC;                      // V stored transposed [B][C][T]
    ushort* Sb = Vt + BTC;                      // B*T*T ushorts
    ushort* xb   = Sb;                          // aliased (dead before scores)
    ushort* Wcat = Sb + BTC;

    dim3 blk(256);

    // 0) fp32 -> bf16 (single fused launch)
    cvt_all<<<dim3(5632), blk, 0, stream>>>(x, Wk, Wq, Wv, xb, Wcat);

    // 1) fused QKV projection, 256x256 tiles, 8 waves, 4-slot ring
    qkv_gemm256<<<dim3(384), dim3(512), 0, stream>>>(xb, Wcat, bk, bq, bv, Kb, Qb, Vt);

    // 2) scores (lower-triangle blocks only)
    gemm_ring<1><<<dim3(544), blk, 0, stream>>>(Kb, Qb, Vt, Sb, out);

    // 3) causal row softmax
    softmax_rows<<<dim3(B * T), blk, 0, stream>>>(Sb, T);

    // 4) y = P @ V (K clipped to causal extent)
    gemm_ring<2><<<dim3(512), blk, 0, stream>>>(Kb, Qb, Vt, Sb, out);
}

// Round 7
// 137.242 us; speedup vs baseline: 1.1228x; 1.1228x over previous
//
#include <hip/hip_runtime.h>
#include <hip/hip_bf16.h>

typedef __attribute__((ext_vector_type(8))) short short8;
typedef __attribute__((ext_vector_type(4))) float f32x4;

// ---------------- helpers ----------------
__device__ __forceinline__ ushort f2b(float f) {
    __hip_bfloat16 h = __float2bfloat16(f);
    return *reinterpret_cast<ushort*>(&h);
}
__device__ __forceinline__ float b2f(ushort u) {
    return __uint_as_float(((unsigned)u) << 16);
}
__device__ __forceinline__ void gload16(const ushort* g, ushort* l) {
    __builtin_amdgcn_global_load_lds(
        (const __attribute__((address_space(1))) void*)g,
        (__attribute__((address_space(3))) void*)l, 16, 0, 0);
}

// ============================================================================
// QKV: 256x128-tile NT GEMM, BK=64, 2-phase double-buffer, counted vmcnt.
// (exact r5 revert — measured 65.2 us / 790 TF)
// ============================================================================
__global__ __launch_bounds__(512, 1) void qkv_gemm256(
    const ushort* __restrict__ xb, const ushort* __restrict__ Wcat,
    const float* __restrict__ bk, const float* __restrict__ bq, const float* __restrict__ bv,
    ushort* __restrict__ Kb, ushort* __restrict__ Qb, ushort* __restrict__ Vt) {
    constexpr int T = 2048, C = 1024, K = 1024, NT = 16;
    __shared__ ushort smem[49152];  // 96 KB

    const int tid = threadIdx.x;
    const int l = tid & 63, w = tid >> 6;
    const int wm = (w >> 2) * 128, wn = (w & 3) * 32;
    const int lr = l & 15, lk = l >> 4;

    const int b = blockIdx.x;                  // 768 = 8*96
    const int wg = (b & 7) * 96 + (b >> 3);    // XCD-bijective
    const int m0 = (wg / 24) * 256, n0 = (wg % 24) * 128;

    const int srow = w * 16 + (l >> 2);                      // 0..127
    const int scb = ((l & 3) << 4) ^ ((l & 32) ? 32 : 0);    // swizzled byte col
    const ushort* gA = xb + (size_t)(m0 + srow) * K + (scb >> 1);
    const ushort* gB = Wcat + (size_t)(n0 + srow) * K + (scb >> 1);

    const int LB = lr * 32 + ((lk << 3) ^ ((lr >= 8) ? 16 : 0));

    f32x4 acc[8][2] = {};

#define STAGEQ(u1, ks)                                                    \
    {                                                                     \
        ushort* _base = smem + ((u1) & 1) * 24576 + (ks) * 12288;         \
        const int _ko = (u1) * 64 + (ks) * 32;                            \
        ushort* _da = _base + w * 512;                                    \
        gload16(gA + _ko, _da);                                           \
        gload16(gA + (size_t)128 * K + _ko, _da + 4096);                  \
        gload16(gB + _ko, _base + 8192 + w * 512);                        \
    }

    STAGEQ(0, 0);
    STAGEQ(0, 1);

    for (int u = 0; u < NT; ++u) {
        const ushort* buf = smem + (u & 1) * 24576;
        // ---- phase 0 ----
        asm volatile("s_waitcnt vmcnt(3)" ::: "memory");
        __builtin_amdgcn_s_barrier();
        asm volatile("" ::: "memory");
        {
            const ushort* Ab = buf + (wm >> 4) * 512 + LB;
            const ushort* Bb = buf + 8192 + (wn >> 4) * 512 + LB;
            short8 a[8], bf2[2];
#pragma unroll
            for (int f = 0; f < 8; ++f) a[f] = *reinterpret_cast<const short8*>(Ab + f * 512);
            bf2[0] = *reinterpret_cast<const short8*>(Bb);
            bf2[1] = *reinterpret_cast<const short8*>(Bb + 512);
            if (u + 1 < NT) STAGEQ(u + 1, 0);
            __builtin_amdgcn_s_setprio(1);
#pragma unroll
            for (int f = 0; f < 8; ++f)
#pragma unroll
                for (int g = 0; g < 2; ++g)
                    acc[f][g] = __builtin_amdgcn_mfma_f32_16x16x32_bf16(a[f], bf2[g], acc[f][g], 0, 0, 0);
            __builtin_amdgcn_s_setprio(0);
        }
        // ---- phase 1 ----
        if (u + 1 < NT) asm volatile("s_waitcnt vmcnt(3)" ::: "memory");
        else            asm volatile("s_waitcnt vmcnt(0)" ::: "memory");
        __builtin_amdgcn_s_barrier();
        asm volatile("" ::: "memory");
        {
            const ushort* Ab = buf + 12288 + (wm >> 4) * 512 + LB;
            const ushort* Bb = buf + 12288 + 8192 + (wn >> 4) * 512 + LB;
            short8 a[8], bf2[2];
#pragma unroll
            for (int f = 0; f < 8; ++f) a[f] = *reinterpret_cast<const short8*>(Ab + f * 512);
            bf2[0] = *reinterpret_cast<const short8*>(Bb);
            bf2[1] = *reinterpret_cast<const short8*>(Bb + 512);
            if (u + 1 < NT) STAGEQ(u + 1, 1);
            __builtin_amdgcn_s_setprio(1);
#pragma unroll
            for (int f = 0; f < 8; ++f)
#pragma unroll
                for (int g = 0; g < 2; ++g)
                    acc[f][g] = __builtin_amdgcn_mfma_f32_16x16x32_bf16(a[f], bf2[g], acc[f][g], 0, 0, 0);
            __builtin_amdgcn_s_setprio(0);
        }
    }
#undef STAGEQ

    const int zsel = n0 >> 10;
    const int c0 = (n0 & 1023) + wn;
    if (zsel < 2) {
        ushort* O = (zsel == 0) ? Kb : Qb;
        const float* bias = (zsel == 0) ? bk : bq;
#pragma unroll
        for (int f = 0; f < 8; ++f)
#pragma unroll
            for (int g = 0; g < 2; ++g) {
                const int gc = c0 + g * 16 + lr;
                const float badd = bias[gc];
#pragma unroll
                for (int rr = 0; rr < 4; ++rr) {
                    const int gr = m0 + wm + f * 16 + lk * 4 + rr;
                    O[(size_t)gr * C + gc] = f2b(acc[f][g][rr] + badd);
                }
            }
    } else {
        const int zb = (m0 + wm) >> 11;
        const int s0 = (m0 + wm) & 2047;
        ushort* Vz = Vt + (size_t)zb * C * T;
#pragma unroll
        for (int f = 0; f < 8; ++f)
#pragma unroll
            for (int g = 0; g < 2; ++g) {
                const int gc = c0 + g * 16 + lr;
                const float badd = bv[gc];
                const int s = s0 + f * 16 + lk * 4;
                ushort tmp[4];
#pragma unroll
                for (int rr = 0; rr < 4; ++rr) tmp[rr] = f2b(acc[f][g][rr] + badd);
                *reinterpret_cast<uint2*>(Vz + (size_t)gc * T + s) =
                    *reinterpret_cast<uint2*>(tmp);
            }
    }
}

// ============================================================================
// 3-slot ring 128x128 NT GEMM for scores / PV (r4-proven skeleton).
// MODE 1 = scores: writes p' = exp(s/32) (0 above diag in diag blocks).
// MODE 2 = PV: extra ones-column MFMA accumulates row-sums of P';
//          epilogue writes y = acc / rowsum (softmax fused, no extra pass).
// ============================================================================
template <int MODE>
__global__ __launch_bounds__(256, 3) void gemm_ring(
    const ushort* __restrict__ Kb, const ushort* __restrict__ Qb,
    const ushort* __restrict__ Vt, ushort* __restrict__ Sb, float* __restrict__ out) {
    constexpr int T = 2048, C = 1024;
    __shared__ ushort smem[24576];  // 48 KB

    const int tid = threadIdx.x;
    const int l = tid & 63, w = tid >> 6;
    const int wm = (w >> 1) * 64, wn = (w & 1) * 64;
    const int lr = l & 15, lk = l >> 4;

    int m0, n0, nt, iblk = 0, jblk = 0, z = 0;
    const ushort *Au, *Bu;
    int ldA, ldB;
    if constexpr (MODE == 1) {
        const int wg0 = blockIdx.x;                  // 544 = 8*68
        const int wg = (wg0 & 7) * 68 + (wg0 >> 3);
        z = wg / 136; const int t136 = wg % 136;
        int i = (int)((sqrtf(8.f * t136 + 1.f) - 1.f) * 0.5f);
        while ((i + 1) * (i + 2) / 2 <= t136) ++i;
        while (i * (i + 1) / 2 > t136) --i;
        const int j = t136 - i * (i + 1) / 2;
        iblk = i; jblk = j;
        m0 = i * 128; n0 = j * 128;
        Au = Qb + (size_t)z * T * C + (size_t)m0 * C; ldA = C;
        Bu = Kb + (size_t)z * T * C + (size_t)n0 * C; ldB = C;
        nt = 32;
    } else {
        const int wg0 = blockIdx.x;                  // 512 = 8*64
        const int wg = (wg0 & 7) * 64 + (wg0 >> 3);
        const int half = wg >> 8, s2 = wg & 255;
        z = s2 >> 6; const int r6 = s2 & 63;
        const int nb = r6 & 7, ii = r6 >> 3;
        const int i = half ? (15 - ii) : ii;
        iblk = i;
        m0 = i * 128; n0 = nb * 128;
        Au = Sb + (size_t)z * T * T + (size_t)m0 * T; ldA = T;
        Bu = Vt + (size_t)z * C * T + (size_t)n0 * T; ldB = T;
        nt = 4 * (i + 1);
    }

    const int srow = w * 16 + (l >> 2);
    const int scb = ((l & 3) << 4) ^ ((l >= 32) ? 32 : 0);
    const ushort* gA = Au + (size_t)srow * ldA + (scb >> 1);
    const ushort* gB = Bu + (size_t)srow * ldB + (scb >> 1);
    const size_t a64 = (size_t)64 * ldA, b64 = (size_t)64 * ldB;
    const int LBu = lr * 32 + ((lk << 3) ^ ((lr >= 8) ? 16 : 0));

    f32x4 acc[4][4] = {};
    f32x4 acc1[4] = {};   // MODE 2: row-sums of P' via ones-column MFMA
    short8 ones;
#pragma unroll
    for (int q = 0; q < 8; ++q) ones[q] = (short)0x3F80;  // bf16 1.0

#define STAGE(tt, sl)                                                    \
    {                                                                    \
        const int _ko = (tt) * 32;                                       \
        ushort* _d = smem + (sl) * 8192 + w * 512;                       \
        gload16(gA + _ko,        _d);                                    \
        gload16(gA + a64 + _ko,  _d + 2048);                             \
        gload16(gB + _ko,        _d + 4096);                             \
        gload16(gB + b64 + _ko,  _d + 6144);                             \
    }

    STAGE(0, 0);
    STAGE(1, 1);
    asm volatile("s_waitcnt vmcnt(4)" ::: "memory");
    __builtin_amdgcn_s_barrier();
    asm volatile("" ::: "memory");

    int sc = 0, ss = 2;
    for (int t = 0; t < nt; ++t) {
        const ushort* As = smem + sc * 8192 + (wm >> 4) * 512 + LBu;
        const ushort* Bs = smem + sc * 8192 + 4096 + (wn >> 4) * 512 + LBu;
        short8 af[4], bf[4];
#pragma unroll
        for (int q = 0; q < 4; ++q) {
            af[q] = *reinterpret_cast<const short8*>(As + q * 512);
            bf[q] = *reinterpret_cast<const short8*>(Bs + q * 512);
        }
        if (t + 2 < nt) STAGE(t + 2, ss);
        __builtin_amdgcn_s_setprio(1);
#pragma unroll
        for (int mf = 0; mf < 4; ++mf)
#pragma unroll
            for (int nf = 0; nf < 4; ++nf)
                acc[mf][nf] = __builtin_amdgcn_mfma_f32_16x16x32_bf16(af[mf], bf[nf], acc[mf][nf], 0, 0, 0);
        if constexpr (MODE == 2) {
#pragma unroll
            for (int mf = 0; mf < 4; ++mf)
                acc1[mf] = __builtin_amdgcn_mfma_f32_16x16x32_bf16(af[mf], ones, acc1[mf], 0, 0, 0);
        }
        __builtin_amdgcn_s_setprio(0);
        if (t + 1 < nt) {
            if (t + 2 < nt) asm volatile("s_waitcnt vmcnt(4)" ::: "memory");
            else            asm volatile("s_waitcnt vmcnt(0)" ::: "memory");
            __builtin_amdgcn_s_barrier();
            asm volatile("" ::: "memory");
        }
        sc = (sc == 2) ? 0 : sc + 1;
        ss = (ss == 2) ? 0 : ss + 1;
    }
#undef STAGE

    if constexpr (MODE == 1) {
        // write p' = exp(s/32); diag blocks write 0 above the diagonal
        ushort* Sp = Sb + (size_t)z * T * T;
        const bool diag = (iblk == jblk);
#pragma unroll
        for (int mf = 0; mf < 4; ++mf)
#pragma unroll
            for (int nf = 0; nf < 4; ++nf) {
                const int gc = n0 + wn + nf * 16 + lr;
#pragma unroll
                for (int rr = 0; rr < 4; ++rr) {
                    const int gr = m0 + wm + mf * 16 + lk * 4 + rr;
                    float p = __expf(acc[mf][nf][rr] * 0.03125f);
                    if (diag && gc > gr) p = 0.f;
                    Sp[(size_t)gr * T + gc] = f2b(p);
                }
            }
    } else {
        // y = acc / rowsum  (rowsum in acc1: D-frag rows == epilogue rows)
        float* Op = out + (size_t)z * T * C;
#pragma unroll
        for (int mf = 0; mf < 4; ++mf)
#pragma unroll
            for (int rr = 0; rr < 4; ++rr) {
                const int gr = m0 + wm + mf * 16 + lk * 4 + rr;
                const float inv = 1.0f / acc1[mf][rr];
#pragma unroll
                for (int nf = 0; nf < 4; ++nf) {
                    const int gc = n0 + wn + nf * 16 + lr;
                    Op[(size_t)gr * C + gc] = acc[mf][nf][rr] * inv;
                }
            }
    }
}

// ---- fused fp32 -> bf16 convert for x, Wk, Wq, Wv ----
__global__ __launch_bounds__(256) void cvt_all(
    const float* __restrict__ x, const float* __restrict__ Wk,
    const float* __restrict__ Wq, const float* __restrict__ Wv,
    ushort* __restrict__ xb, ushort* __restrict__ Wcat) {
    constexpr int C = 1024;
    constexpr int NX = 8388608 / 8, NW = C * C / 8;
    int i = blockIdx.x * 256 + threadIdx.x;
    const float* src; ushort* dst;
    if (i < NX)               { src = x;  dst = xb; }
    else if (i < NX + NW)     { src = Wk; dst = Wcat;                 i -= NX; }
    else if (i < NX + 2 * NW) { src = Wq; dst = Wcat + (size_t)C * C; i -= NX + NW; }
    else                      { src = Wv; dst = Wcat + 2 * (size_t)C * C; i -= NX + 2 * NW; }
    const float4* p = reinterpret_cast<const float4*>(src) + (size_t)i * 2;
    float4 a = p[0], b = p[1];
    ushort o[8] = {f2b(a.x), f2b(a.y), f2b(a.z), f2b(a.w),
                   f2b(b.x), f2b(b.y), f2b(b.z), f2b(b.w)};
    reinterpret_cast<uint4*>(dst)[i] = *reinterpret_cast<uint4*>(o);
}

extern "C" void kernel_launch(void* const* d_in, const int* in_sizes, int n_in,
                              void* d_out, int out_size, void* d_ws, size_t ws_size,
                              hipStream_t stream) {
    const float* x  = (const float*)d_in[0];
    const float* Wk = (const float*)d_in[1];
    const float* bk = (const float*)d_in[2];
    const float* Wq = (const float*)d_in[3];
    const float* bq = (const float*)d_in[4];
    const float* Wv = (const float*)d_in[5];
    const float* bv = (const float*)d_in[6];
    float* out = (float*)d_out;

    constexpr int B = 4, T = 2048, C = 1024;
    constexpr size_t BTC = (size_t)B * T * C;  // 8388608

    ushort* Kb = (ushort*)d_ws;
    ushort* Qb = Kb + BTC;
    ushort* Vt = Qb + BTC;                      // V stored transposed [B][C][T]
    ushort* Sb = Vt + BTC;                      // B*T*T ushorts (holds P' = exp)
    ushort* xb   = Sb;                          // aliased (dead before scores)
    ushort* Wcat = Sb + BTC;

    dim3 blk(256);

    // 0) fp32 -> bf16 (single fused launch)
    cvt_all<<<dim3(5632), blk, 0, stream>>>(x, Wk, Wq, Wv, xb, Wcat);

    // 1) fused QKV projection (r5 structure, 256x128, 2-phase dbuf)
    qkv_gemm256<<<dim3(768), dim3(512), 0, stream>>>(xb, Wcat, bk, bq, bv, Kb, Qb, Vt);

    // 2) scores -> P' = exp(s/32), causal (lower-triangle blocks; full diag tiles)
    gemm_ring<1><<<dim3(544), blk, 0, stream>>>(Kb, Qb, Vt, Sb, out);

    // 3) y = (P' @ V) / rowsum(P')  -- softmax normalization fused via ones-MFMA
    gemm_ring<2><<<dim3(512), blk, 0, stream>>>(Kb, Qb, Vt, Sb, out);
}

// Round 8
// 137.032 us; speedup vs baseline: 1.1245x; 1.0015x over previous
//
#include <hip/hip_runtime.h>
#include <hip/hip_bf16.h>

typedef __attribute__((ext_vector_type(8))) short short8;
typedef __attribute__((ext_vector_type(4))) float f32x4;

// ---------------- helpers ----------------
__device__ __forceinline__ ushort f2b(float f) {
    __hip_bfloat16 h = __float2bfloat16(f);
    return *reinterpret_cast<ushort*>(&h);
}
__device__ __forceinline__ float b2f(ushort u) {
    return __uint_as_float(((unsigned)u) << 16);
}
__device__ __forceinline__ void gload16(const ushort* g, ushort* l) {
    __builtin_amdgcn_global_load_lds(
        (const __attribute__((address_space(1))) void*)g,
        (__attribute__((address_space(3))) void*)l, 16, 0, 0);
}

// ============================================================================
// QKV: 256x128-tile NT GEMM, BK=64, 2-phase double-buffer, counted vmcnt.
// r5 structure, but waves partitioned 4M x 2N with 64x64 per-wave output
// (acc[4][4]): LDS ds_read traffic per K-tile drops 160KB -> 128KB
// (MFMA per b128-read 1.6 -> 2.0); staging/swizzle/ledger unchanged.
// ============================================================================
__global__ __launch_bounds__(512, 1) void qkv_gemm256(
    const ushort* __restrict__ xb, const ushort* __restrict__ Wcat,
    const float* __restrict__ bk, const float* __restrict__ bq, const float* __restrict__ bv,
    ushort* __restrict__ Kb, ushort* __restrict__ Qb, ushort* __restrict__ Vt) {
    constexpr int T = 2048, C = 1024, K = 1024, NT = 16;
    __shared__ ushort smem[49152];  // 96 KB

    const int tid = threadIdx.x;
    const int l = tid & 63, w = tid >> 6;
    const int wm = (w >> 1) * 64, wn = (w & 1) * 64;   // 4M x 2N, 64x64/wave
    const int lr = l & 15, lk = l >> 4;

    const int b = blockIdx.x;                  // 768 = 8*96
    const int wg = (b & 7) * 96 + (b >> 3);    // XCD-bijective
    const int m0 = (wg / 24) * 256, n0 = (wg % 24) * 128;

    const int srow = w * 16 + (l >> 2);                      // 0..127
    const int scb = ((l & 3) << 4) ^ ((l & 32) ? 32 : 0);    // swizzled byte col
    const ushort* gA = xb + (size_t)(m0 + srow) * K + (scb >> 1);
    const ushort* gB = Wcat + (size_t)(n0 + srow) * K + (scb >> 1);

    const int LB = lr * 32 + ((lk << 3) ^ ((lr >= 8) ? 16 : 0));

    f32x4 acc[4][4] = {};

#define STAGEQ(u1, ks)                                                    \
    {                                                                     \
        ushort* _base = smem + ((u1) & 1) * 24576 + (ks) * 12288;         \
        const int _ko = (u1) * 64 + (ks) * 32;                            \
        ushort* _da = _base + w * 512;                                    \
        gload16(gA + _ko, _da);                                           \
        gload16(gA + (size_t)128 * K + _ko, _da + 4096);                  \
        gload16(gB + _ko, _base + 8192 + w * 512);                        \
    }

    STAGEQ(0, 0);
    STAGEQ(0, 1);

    for (int u = 0; u < NT; ++u) {
        const ushort* buf = smem + (u & 1) * 24576;
        // ---- phase 0 (k-half 0) ----
        asm volatile("s_waitcnt vmcnt(3)" ::: "memory");
        __builtin_amdgcn_s_barrier();
        asm volatile("" ::: "memory");
        {
            const ushort* Ab = buf + (wm >> 4) * 512 + LB;
            const ushort* Bb = buf + 8192 + (wn >> 4) * 512 + LB;
            short8 af[4], bf4[4];
#pragma unroll
            for (int f = 0; f < 4; ++f) af[f] = *reinterpret_cast<const short8*>(Ab + f * 512);
#pragma unroll
            for (int g = 0; g < 4; ++g) bf4[g] = *reinterpret_cast<const short8*>(Bb + g * 512);
            if (u + 1 < NT) STAGEQ(u + 1, 0);
            __builtin_amdgcn_s_setprio(1);
#pragma unroll
            for (int f = 0; f < 4; ++f)
#pragma unroll
                for (int g = 0; g < 4; ++g)
                    acc[f][g] = __builtin_amdgcn_mfma_f32_16x16x32_bf16(af[f], bf4[g], acc[f][g], 0, 0, 0);
            __builtin_amdgcn_s_setprio(0);
        }
        // ---- phase 1 (k-half 1) ----
        if (u + 1 < NT) asm volatile("s_waitcnt vmcnt(3)" ::: "memory");
        else            asm volatile("s_waitcnt vmcnt(0)" ::: "memory");
        __builtin_amdgcn_s_barrier();
        asm volatile("" ::: "memory");
        {
            const ushort* Ab = buf + 12288 + (wm >> 4) * 512 + LB;
            const ushort* Bb = buf + 12288 + 8192 + (wn >> 4) * 512 + LB;
            short8 af[4], bf4[4];
#pragma unroll
            for (int f = 0; f < 4; ++f) af[f] = *reinterpret_cast<const short8*>(Ab + f * 512);
#pragma unroll
            for (int g = 0; g < 4; ++g) bf4[g] = *reinterpret_cast<const short8*>(Bb + g * 512);
            if (u + 1 < NT) STAGEQ(u + 1, 1);
            __builtin_amdgcn_s_setprio(1);
#pragma unroll
            for (int f = 0; f < 4; ++f)
#pragma unroll
                for (int g = 0; g < 4; ++g)
                    acc[f][g] = __builtin_amdgcn_mfma_f32_16x16x32_bf16(af[f], bf4[g], acc[f][g], 0, 0, 0);
            __builtin_amdgcn_s_setprio(0);
        }
    }
#undef STAGEQ

    // ---- epilogue: D col = lane&15, row = (lane>>4)*4 + reg ----
    const int zsel = n0 >> 10;
    const int c0 = (n0 & 1023) + wn;
    if (zsel < 2) {
        ushort* O = (zsel == 0) ? Kb : Qb;
        const float* bias = (zsel == 0) ? bk : bq;
#pragma unroll
        for (int f = 0; f < 4; ++f)
#pragma unroll
            for (int g = 0; g < 4; ++g) {
                const int gc = c0 + g * 16 + lr;
                const float badd = bias[gc];
#pragma unroll
                for (int rr = 0; rr < 4; ++rr) {
                    const int gr = m0 + wm + f * 16 + lk * 4 + rr;
                    O[(size_t)gr * C + gc] = f2b(acc[f][g][rr] + badd);
                }
            }
    } else {
        const int zb = (m0 + wm) >> 11;
        const int s0 = (m0 + wm) & 2047;
        ushort* Vz = Vt + (size_t)zb * C * T;
#pragma unroll
        for (int f = 0; f < 4; ++f)
#pragma unroll
            for (int g = 0; g < 4; ++g) {
                const int gc = c0 + g * 16 + lr;
                const float badd = bv[gc];
                const int s = s0 + f * 16 + lk * 4;
                ushort tmp[4];
#pragma unroll
                for (int rr = 0; rr < 4; ++rr) tmp[rr] = f2b(acc[f][g][rr] + badd);
                *reinterpret_cast<uint2*>(Vz + (size_t)gc * T + s) =
                    *reinterpret_cast<uint2*>(tmp);
            }
    }
}

// ============================================================================
// 3-slot ring 128x128 NT GEMM for scores / PV (r7-proven).
// MODE 1 = scores: writes p' = exp(s/32) (0 above diag in diag blocks).
// MODE 2 = PV: ones-column MFMA row-sums; epilogue y = acc / rowsum.
// ============================================================================
template <int MODE>
__global__ __launch_bounds__(256, 3) void gemm_ring(
    const ushort* __restrict__ Kb, const ushort* __restrict__ Qb,
    const ushort* __restrict__ Vt, ushort* __restrict__ Sb, float* __restrict__ out) {
    constexpr int T = 2048, C = 1024;
    __shared__ ushort smem[24576];  // 48 KB

    const int tid = threadIdx.x;
    const int l = tid & 63, w = tid >> 6;
    const int wm = (w >> 1) * 64, wn = (w & 1) * 64;
    const int lr = l & 15, lk = l >> 4;

    int m0, n0, nt, iblk = 0, jblk = 0, z = 0;
    const ushort *Au, *Bu;
    int ldA, ldB;
    if constexpr (MODE == 1) {
        const int wg0 = blockIdx.x;                  // 544 = 8*68
        const int wg = (wg0 & 7) * 68 + (wg0 >> 3);
        z = wg / 136; const int t136 = wg % 136;
        int i = (int)((sqrtf(8.f * t136 + 1.f) - 1.f) * 0.5f);
        while ((i + 1) * (i + 2) / 2 <= t136) ++i;
        while (i * (i + 1) / 2 > t136) --i;
        const int j = t136 - i * (i + 1) / 2;
        iblk = i; jblk = j;
        m0 = i * 128; n0 = j * 128;
        Au = Qb + (size_t)z * T * C + (size_t)m0 * C; ldA = C;
        Bu = Kb + (size_t)z * T * C + (size_t)n0 * C; ldB = C;
        nt = 32;
    } else {
        const int wg0 = blockIdx.x;                  // 512 = 8*64
        const int wg = (wg0 & 7) * 64 + (wg0 >> 3);
        const int half = wg >> 8, s2 = wg & 255;
        z = s2 >> 6; const int r6 = s2 & 63;
        const int nb = r6 & 7, ii = r6 >> 3;
        const int i = half ? (15 - ii) : ii;
        iblk = i;
        m0 = i * 128; n0 = nb * 128;
        Au = Sb + (size_t)z * T * T + (size_t)m0 * T; ldA = T;
        Bu = Vt + (size_t)z * C * T + (size_t)n0 * T; ldB = T;
        nt = 4 * (i + 1);
    }

    const int srow = w * 16 + (l >> 2);
    const int scb = ((l & 3) << 4) ^ ((l >= 32) ? 32 : 0);
    const ushort* gA = Au + (size_t)srow * ldA + (scb >> 1);
    const ushort* gB = Bu + (size_t)srow * ldB + (scb >> 1);
    const size_t a64 = (size_t)64 * ldA, b64 = (size_t)64 * ldB;
    const int LBu = lr * 32 + ((lk << 3) ^ ((lr >= 8) ? 16 : 0));

    f32x4 acc[4][4] = {};
    f32x4 acc1[4] = {};
    short8 ones;
#pragma unroll
    for (int q = 0; q < 8; ++q) ones[q] = (short)0x3F80;  // bf16 1.0

#define STAGE(tt, sl)                                                    \
    {                                                                    \
        const int _ko = (tt) * 32;                                       \
        ushort* _d = smem + (sl) * 8192 + w * 512;                       \
        gload16(gA + _ko,        _d);                                    \
        gload16(gA + a64 + _ko,  _d + 2048);                             \
        gload16(gB + _ko,        _d + 4096);                             \
        gload16(gB + b64 + _ko,  _d + 6144);                             \
    }

    STAGE(0, 0);
    STAGE(1, 1);
    asm volatile("s_waitcnt vmcnt(4)" ::: "memory");
    __builtin_amdgcn_s_barrier();
    asm volatile("" ::: "memory");

    int sc = 0, ss = 2;
    for (int t = 0; t < nt; ++t) {
        const ushort* As = smem + sc * 8192 + (wm >> 4) * 512 + LBu;
        const ushort* Bs = smem + sc * 8192 + 4096 + (wn >> 4) * 512 + LBu;
        short8 af[4], bf[4];
#pragma unroll
        for (int q = 0; q < 4; ++q) {
            af[q] = *reinterpret_cast<const short8*>(As + q * 512);
            bf[q] = *reinterpret_cast<const short8*>(Bs + q * 512);
        }
        if (t + 2 < nt) STAGE(t + 2, ss);
        __builtin_amdgcn_s_setprio(1);
#pragma unroll
        for (int mf = 0; mf < 4; ++mf)
#pragma unroll
            for (int nf = 0; nf < 4; ++nf)
                acc[mf][nf] = __builtin_amdgcn_mfma_f32_16x16x32_bf16(af[mf], bf[nf], acc[mf][nf], 0, 0, 0);
        if constexpr (MODE == 2) {
#pragma unroll
            for (int mf = 0; mf < 4; ++mf)
                acc1[mf] = __builtin_amdgcn_mfma_f32_16x16x32_bf16(af[mf], ones, acc1[mf], 0, 0, 0);
        }
        __builtin_amdgcn_s_setprio(0);
        if (t + 1 < nt) {
            if (t + 2 < nt) asm volatile("s_waitcnt vmcnt(4)" ::: "memory");
            else            asm volatile("s_waitcnt vmcnt(0)" ::: "memory");
            __builtin_amdgcn_s_barrier();
            asm volatile("" ::: "memory");
        }
        sc = (sc == 2) ? 0 : sc + 1;
        ss = (ss == 2) ? 0 : ss + 1;
    }
#undef STAGE

    if constexpr (MODE == 1) {
        ushort* Sp = Sb + (size_t)z * T * T;
        const bool diag = (iblk == jblk);
#pragma unroll
        for (int mf = 0; mf < 4; ++mf)
#pragma unroll
            for (int nf = 0; nf < 4; ++nf) {
                const int gc = n0 + wn + nf * 16 + lr;
#pragma unroll
                for (int rr = 0; rr < 4; ++rr) {
                    const int gr = m0 + wm + mf * 16 + lk * 4 + rr;
                    float p = __expf(acc[mf][nf][rr] * 0.03125f);
                    if (diag && gc > gr) p = 0.f;
                    Sp[(size_t)gr * T + gc] = f2b(p);
                }
            }
    } else {
        float* Op = out + (size_t)z * T * C;
#pragma unroll
        for (int mf = 0; mf < 4; ++mf)
#pragma unroll
            for (int rr = 0; rr < 4; ++rr) {
                const int gr = m0 + wm + mf * 16 + lk * 4 + rr;
                const float inv = 1.0f / acc1[mf][rr];
#pragma unroll
                for (int nf = 0; nf < 4; ++nf) {
                    const int gc = n0 + wn + nf * 16 + lr;
                    Op[(size_t)gr * C + gc] = acc[mf][nf][rr] * inv;
                }
            }
    }
}

// ---- fused fp32 -> bf16 convert for x, Wk, Wq, Wv ----
__global__ __launch_bounds__(256) void cvt_all(
    const float* __restrict__ x, const float* __restrict__ Wk,
    const float* __restrict__ Wq, const float* __restrict__ Wv,
    ushort* __restrict__ xb, ushort* __restrict__ Wcat) {
    constexpr int C = 1024;
    constexpr int NX = 8388608 / 8, NW = C * C / 8;
    int i = blockIdx.x * 256 + threadIdx.x;
    const float* src; ushort* dst;
    if (i < NX)               { src = x;  dst = xb; }
    else if (i < NX + NW)     { src = Wk; dst = Wcat;                 i -= NX; }
    else if (i < NX + 2 * NW) { src = Wq; dst = Wcat + (size_t)C * C; i -= NX + NW; }
    else                      { src = Wv; dst = Wcat + 2 * (size_t)C * C; i -= NX + 2 * NW; }
    const float4* p = reinterpret_cast<const float4*>(src) + (size_t)i * 2;
    float4 a = p[0], b = p[1];
    ushort o[8] = {f2b(a.x), f2b(a.y), f2b(a.z), f2b(a.w),
                   f2b(b.x), f2b(b.y), f2b(b.z), f2b(b.w)};
    reinterpret_cast<uint4*>(dst)[i] = *reinterpret_cast<uint4*>(o);
}

extern "C" void kernel_launch(void* const* d_in, const int* in_sizes, int n_in,
                              void* d_out, int out_size, void* d_ws, size_t ws_size,
                              hipStream_t stream) {
    const float* x  = (const float*)d_in[0];
    const float* Wk = (const float*)d_in[1];
    const float* bk = (const float*)d_in[2];
    const float* Wq = (const float*)d_in[3];
    const float* bq = (const float*)d_in[4];
    const float* Wv = (const float*)d_in[5];
    const float* bv = (const float*)d_in[6];
    float* out = (float*)d_out;

    constexpr int B = 4, T = 2048, C = 1024;
    constexpr size_t BTC = (size_t)B * T * C;  // 8388608

    ushort* Kb = (ushort*)d_ws;
    ushort* Qb = Kb + BTC;
    ushort* Vt = Qb + BTC;                      // V stored transposed [B][C][T]
    ushort* Sb = Vt + BTC;                      // B*T*T ushorts (holds P' = exp)
    ushort* xb   = Sb;                          // aliased (dead before scores)
    ushort* Wcat = Sb + BTC;

    dim3 blk(256);

    // 0) fp32 -> bf16 (single fused launch)
    cvt_all<<<dim3(5632), blk, 0, stream>>>(x, Wk, Wq, Wv, xb, Wcat);

    // 1) fused QKV projection (256x128, 2-phase dbuf, 64x64 wave tiles)
    qkv_gemm256<<<dim3(768), dim3(512), 0, stream>>>(xb, Wcat, bk, bq, bv, Kb, Qb, Vt);

    // 2) scores -> P' = exp(s/32), causal (lower-triangle blocks; full diag tiles)
    gemm_ring<1><<<dim3(544), blk, 0, stream>>>(Kb, Qb, Vt, Sb, out);

    // 3) y = (P' @ V) / rowsum(P')  -- softmax normalization fused via ones-MFMA
    gemm_ring<2><<<dim3(512), blk, 0, stream>>>(Kb, Qb, Vt, Sb, out);
}

// Round 9
// 136.551 us; speedup vs baseline: 1.1285x; 1.0035x over previous
//
#include <hip/hip_runtime.h>
#include <hip/hip_bf16.h>

typedef __attribute__((ext_vector_type(8))) short short8;
typedef __attribute__((ext_vector_type(4))) float f32x4;

// ---------------- helpers ----------------
__device__ __forceinline__ ushort f2b(float f) {
    __hip_bfloat16 h = __float2bfloat16(f);
    return *reinterpret_cast<ushort*>(&h);
}
__device__ __forceinline__ float b2f(ushort u) {
    return __uint_as_float(((unsigned)u) << 16);
}
__device__ __forceinline__ void gload16(const ushort* g, ushort* l) {
    __builtin_amdgcn_global_load_lds(
        (const __attribute__((address_space(1))) void*)g,
        (__attribute__((address_space(3))) void*)l, 16, 0, 0);
}

// ============================================================================
// QKV: 256x128-tile NT GEMM, BK=32, 3-slot LDS ring (72 KB -> 2 blocks/CU),
// single barrier per K-tile, depth-2 prefetch, counted vmcnt (r4-proven
// ledger: prologue 2 tiles + vmcnt(3); loop reads -> STAGE(t+2) -> MFMA ->
// vmcnt(3 or 0) -> barrier). 512 thr = 8 waves (4M x 2N), 64x64 per wave.
// 2 blocks/CU co-residency fills the global-load latency shadow that capped
// r5/r8 (1 block/CU) at ~65 us.
// ============================================================================
__global__ __launch_bounds__(512, 4) void qkv_gemm256(
    const ushort* __restrict__ xb, const ushort* __restrict__ Wcat,
    const float* __restrict__ bk, const float* __restrict__ bq, const float* __restrict__ bv,
    ushort* __restrict__ Kb, ushort* __restrict__ Qb, ushort* __restrict__ Vt) {
    constexpr int T = 2048, C = 1024, K = 1024, NT = 32;
    __shared__ ushort smem[36864];  // 72 KB = 3 slots x 12288 ushorts (24 KB)

    const int tid = threadIdx.x;
    const int l = tid & 63, w = tid >> 6;
    const int wm = (w >> 1) * 64, wn = (w & 1) * 64;   // 4M x 2N, 64x64/wave
    const int lr = l & 15, lk = l >> 4;

    const int b = blockIdx.x;                  // 768 = 8*96
    const int wg = (b & 7) * 96 + (b >> 3);    // XCD-bijective
    const int m0 = (wg / 24) * 256, n0 = (wg % 24) * 128;

    // staging coords (pre-swizzled source; linear LDS dest). Unit = 128 rows
    // x 64B = 8 KB = 512 thr x 16B. A = 2 units (rows 0-127, 128-255), B = 1.
    const int srow = w * 16 + (l >> 2);                      // 0..127
    const int scb = ((l & 3) << 4) ^ ((l & 32) ? 32 : 0);    // swizzled byte col
    const ushort* gA = xb + (size_t)(m0 + srow) * K + (scb >> 1);
    const ushort* gB = Wcat + (size_t)(n0 + srow) * K + (scb >> 1);

    // ds_read per-lane base (ushort units), swizzled
    const int LB = lr * 32 + ((lk << 3) ^ ((lr >= 8) ? 16 : 0));

    f32x4 acc[4][4] = {};

    // slot sl at sl*12288: A subtiles 0-15 at 0..8191 (unit0 0..4095,
    // unit1 4096..8191), B subtiles at 8192..12287.
#define STAGEQ(tt, sl)                                                    \
    {                                                                     \
        const int _ko = (tt) * 32;                                        \
        ushort* _s = smem + (sl) * 12288 + w * 512;                       \
        gload16(gA + _ko,                   _s);                          \
        gload16(gA + (size_t)128 * K + _ko, _s + 4096);                   \
        gload16(gB + _ko,                   _s + 8192);                   \
    }

    STAGEQ(0, 0);
    STAGEQ(1, 1);
    asm volatile("s_waitcnt vmcnt(3)" ::: "memory");   // drain tile 0, keep tile 1
    __builtin_amdgcn_s_barrier();
    asm volatile("" ::: "memory");

    int sc = 0, ss = 2;
    for (int t = 0; t < NT; ++t) {
        const ushort* slot = smem + sc * 12288;
        const ushort* Ab = slot + (wm >> 4) * 512 + LB;
        const ushort* Bb = slot + 8192 + (wn >> 4) * 512 + LB;
        short8 af[4], bf4[4];
#pragma unroll
        for (int f = 0; f < 4; ++f) af[f] = *reinterpret_cast<const short8*>(Ab + f * 512);
#pragma unroll
        for (int g = 0; g < 4; ++g) bf4[g] = *reinterpret_cast<const short8*>(Bb + g * 512);
        if (t + 2 < NT) STAGEQ(t + 2, ss);
        __builtin_amdgcn_s_setprio(1);
#pragma unroll
        for (int f = 0; f < 4; ++f)
#pragma unroll
            for (int g = 0; g < 4; ++g)
                acc[f][g] = __builtin_amdgcn_mfma_f32_16x16x32_bf16(af[f], bf4[g], acc[f][g], 0, 0, 0);
        __builtin_amdgcn_s_setprio(0);
        if (t + 1 < NT) {
            if (t + 2 < NT) asm volatile("s_waitcnt vmcnt(3)" ::: "memory");
            else            asm volatile("s_waitcnt vmcnt(0)" ::: "memory");
            __builtin_amdgcn_s_barrier();
            asm volatile("" ::: "memory");
        }
        sc = (sc == 2) ? 0 : sc + 1;
        ss = (ss == 2) ? 0 : ss + 1;
    }
#undef STAGEQ

    // ---- epilogue: D col = lane&15, row = (lane>>4)*4 + reg ----
    const int zsel = n0 >> 10;
    const int c0 = (n0 & 1023) + wn;
    if (zsel < 2) {
        ushort* O = (zsel == 0) ? Kb : Qb;
        const float* bias = (zsel == 0) ? bk : bq;
#pragma unroll
        for (int f = 0; f < 4; ++f)
#pragma unroll
            for (int g = 0; g < 4; ++g) {
                const int gc = c0 + g * 16 + lr;
                const float badd = bias[gc];
#pragma unroll
                for (int rr = 0; rr < 4; ++rr) {
                    const int gr = m0 + wm + f * 16 + lk * 4 + rr;
                    O[(size_t)gr * C + gc] = f2b(acc[f][g][rr] + badd);
                }
            }
    } else {
        const int zb = (m0 + wm) >> 11;
        const int s0 = (m0 + wm) & 2047;
        ushort* Vz = Vt + (size_t)zb * C * T;
#pragma unroll
        for (int f = 0; f < 4; ++f)
#pragma unroll
            for (int g = 0; g < 4; ++g) {
                const int gc = c0 + g * 16 + lr;
                const float badd = bv[gc];
                const int s = s0 + f * 16 + lk * 4;
                ushort tmp[4];
#pragma unroll
                for (int rr = 0; rr < 4; ++rr) tmp[rr] = f2b(acc[f][g][rr] + badd);
                *reinterpret_cast<uint2*>(Vz + (size_t)gc * T + s) =
                    *reinterpret_cast<uint2*>(tmp);
            }
    }
}

// ============================================================================
// 3-slot ring 128x128 NT GEMM for scores / PV (r7/r8-proven, unchanged).
// MODE 1 = scores: writes p' = exp(s/32) (0 above diag in diag blocks).
// MODE 2 = PV: ones-column MFMA row-sums; epilogue y = acc / rowsum.
// ============================================================================
template <int MODE>
__global__ __launch_bounds__(256, 3) void gemm_ring(
    const ushort* __restrict__ Kb, const ushort* __restrict__ Qb,
    const ushort* __restrict__ Vt, ushort* __restrict__ Sb, float* __restrict__ out) {
    constexpr int T = 2048, C = 1024;
    __shared__ ushort smem[24576];  // 48 KB

    const int tid = threadIdx.x;
    const int l = tid & 63, w = tid >> 6;
    const int wm = (w >> 1) * 64, wn = (w & 1) * 64;
    const int lr = l & 15, lk = l >> 4;

    int m0, n0, nt, iblk = 0, jblk = 0, z = 0;
    const ushort *Au, *Bu;
    int ldA, ldB;
    if constexpr (MODE == 1) {
        const int wg0 = blockIdx.x;                  // 544 = 8*68
        const int wg = (wg0 & 7) * 68 + (wg0 >> 3);
        z = wg / 136; const int t136 = wg % 136;
        int i = (int)((sqrtf(8.f * t136 + 1.f) - 1.f) * 0.5f);
        while ((i + 1) * (i + 2) / 2 <= t136) ++i;
        while (i * (i + 1) / 2 > t136) --i;
        const int j = t136 - i * (i + 1) / 2;
        iblk = i; jblk = j;
        m0 = i * 128; n0 = j * 128;
        Au = Qb + (size_t)z * T * C + (size_t)m0 * C; ldA = C;
        Bu = Kb + (size_t)z * T * C + (size_t)n0 * C; ldB = C;
        nt = 32;
    } else {
        const int wg0 = blockIdx.x;                  // 512 = 8*64
        const int wg = (wg0 & 7) * 64 + (wg0 >> 3);
        const int half = wg >> 8, s2 = wg & 255;
        z = s2 >> 6; const int r6 = s2 & 63;
        const int nb = r6 & 7, ii = r6 >> 3;
        const int i = half ? (15 - ii) : ii;
        iblk = i;
        m0 = i * 128; n0 = nb * 128;
        Au = Sb + (size_t)z * T * T + (size_t)m0 * T; ldA = T;
        Bu = Vt + (size_t)z * C * T + (size_t)n0 * T; ldB = T;
        nt = 4 * (i + 1);
    }

    const int srow = w * 16 + (l >> 2);
    const int scb = ((l & 3) << 4) ^ ((l >= 32) ? 32 : 0);
    const ushort* gA = Au + (size_t)srow * ldA + (scb >> 1);
    const ushort* gB = Bu + (size_t)srow * ldB + (scb >> 1);
    const size_t a64 = (size_t)64 * ldA, b64 = (size_t)64 * ldB;
    const int LBu = lr * 32 + ((lk << 3) ^ ((lr >= 8) ? 16 : 0));

    f32x4 acc[4][4] = {};
    f32x4 acc1[4] = {};
    short8 ones;
#pragma unroll
    for (int q = 0; q < 8; ++q) ones[q] = (short)0x3F80;  // bf16 1.0

#define STAGE(tt, sl)                                                    \
    {                                                                    \
        const int _ko = (tt) * 32;                                       \
        ushort* _d = smem + (sl) * 8192 + w * 512;                       \
        gload16(gA + _ko,        _d);                                    \
        gload16(gA + a64 + _ko,  _d + 2048);                             \
        gload16(gB + _ko,        _d + 4096);                             \
        gload16(gB + b64 + _ko,  _d + 6144);                             \
    }

    STAGE(0, 0);
    STAGE(1, 1);
    asm volatile("s_waitcnt vmcnt(4)" ::: "memory");
    __builtin_amdgcn_s_barrier();
    asm volatile("" ::: "memory");

    int sc = 0, ss = 2;
    for (int t = 0; t < nt; ++t) {
        const ushort* As = smem + sc * 8192 + (wm >> 4) * 512 + LBu;
        const ushort* Bs = smem + sc * 8192 + 4096 + (wn >> 4) * 512 + LBu;
        short8 af[4], bf[4];
#pragma unroll
        for (int q = 0; q < 4; ++q) {
            af[q] = *reinterpret_cast<const short8*>(As + q * 512);
            bf[q] = *reinterpret_cast<const short8*>(Bs + q * 512);
        }
        if (t + 2 < nt) STAGE(t + 2, ss);
        __builtin_amdgcn_s_setprio(1);
#pragma unroll
        for (int mf = 0; mf < 4; ++mf)
#pragma unroll
            for (int nf = 0; nf < 4; ++nf)
                acc[mf][nf] = __builtin_amdgcn_mfma_f32_16x16x32_bf16(af[mf], bf[nf], acc[mf][nf], 0, 0, 0);
        if constexpr (MODE == 2) {
#pragma unroll
            for (int mf = 0; mf < 4; ++mf)
                acc1[mf] = __builtin_amdgcn_mfma_f32_16x16x32_bf16(af[mf], ones, acc1[mf], 0, 0, 0);
        }
        __builtin_amdgcn_s_setprio(0);
        if (t + 1 < nt) {
            if (t + 2 < nt) asm volatile("s_waitcnt vmcnt(4)" ::: "memory");
            else            asm volatile("s_waitcnt vmcnt(0)" ::: "memory");
            __builtin_amdgcn_s_barrier();
            asm volatile("" ::: "memory");
        }
        sc = (sc == 2) ? 0 : sc + 1;
        ss = (ss == 2) ? 0 : ss + 1;
    }
#undef STAGE

    if constexpr (MODE == 1) {
        ushort* Sp = Sb + (size_t)z * T * T;
        const bool diag = (iblk == jblk);
#pragma unroll
        for (int mf = 0; mf < 4; ++mf)
#pragma unroll
            for (int nf = 0; nf < 4; ++nf) {
                const int gc = n0 + wn + nf * 16 + lr;
#pragma unroll
                for (int rr = 0; rr < 4; ++rr) {
                    const int gr = m0 + wm + mf * 16 + lk * 4 + rr;
                    float p = __expf(acc[mf][nf][rr] * 0.03125f);
                    if (diag && gc > gr) p = 0.f;
                    Sp[(size_t)gr * T + gc] = f2b(p);
                }
            }
    } else {
        float* Op = out + (size_t)z * T * C;
#pragma unroll
        for (int mf = 0; mf < 4; ++mf)
#pragma unroll
            for (int rr = 0; rr < 4; ++rr) {
                const int gr = m0 + wm + mf * 16 + lk * 4 + rr;
                const float inv = 1.0f / acc1[mf][rr];
#pragma unroll
                for (int nf = 0; nf < 4; ++nf) {
                    const int gc = n0 + wn + nf * 16 + lr;
                    Op[(size_t)gr * C + gc] = acc[mf][nf][rr] * inv;
                }
            }
    }
}

// ---- fused fp32 -> bf16 convert for x, Wk, Wq, Wv ----
__global__ __launch_bounds__(256) void cvt_all(
    const float* __restrict__ x, const float* __restrict__ Wk,
    const float* __restrict__ Wq, const float* __restrict__ Wv,
    ushort* __restrict__ xb, ushort* __restrict__ Wcat) {
    constexpr int C = 1024;
    constexpr int NX = 8388608 / 8, NW = C * C / 8;
    int i = blockIdx.x * 256 + threadIdx.x;
    const float* src; ushort* dst;
    if (i < NX)               { src = x;  dst = xb; }
    else if (i < NX + NW)     { src = Wk; dst = Wcat;                 i -= NX; }
    else if (i < NX + 2 * NW) { src = Wq; dst = Wcat + (size_t)C * C; i -= NX + NW; }
    else                      { src = Wv; dst = Wcat + 2 * (size_t)C * C; i -= NX + 2 * NW; }
    const float4* p = reinterpret_cast<const float4*>(src) + (size_t)i * 2;
    float4 a = p[0], b = p[1];
    ushort o[8] = {f2b(a.x), f2b(a.y), f2b(a.z), f2b(a.w),
                   f2b(b.x), f2b(b.y), f2b(b.z), f2b(b.w)};
    reinterpret_cast<uint4*>(dst)[i] = *reinterpret_cast<uint4*>(o);
}

extern "C" void kernel_launch(void* const* d_in, const int* in_sizes, int n_in,
                              void* d_out, int out_size, void* d_ws, size_t ws_size,
                              hipStream_t stream) {
    const float* x  = (const float*)d_in[0];
    const float* Wk = (const float*)d_in[1];
    const float* bk = (const float*)d_in[2];
    const float* Wq = (const float*)d_in[3];
    const float* bq = (const float*)d_in[4];
    const float* Wv = (const float*)d_in[5];
    const float* bv = (const float*)d_in[6];
    float* out = (float*)d_out;

    constexpr int B = 4, T = 2048, C = 1024;
    constexpr size_t BTC = (size_t)B * T * C;  // 8388608

    ushort* Kb = (ushort*)d_ws;
    ushort* Qb = Kb + BTC;
    ushort* Vt = Qb + BTC;                      // V stored transposed [B][C][T]
    ushort* Sb = Vt + BTC;                      // B*T*T ushorts (holds P' = exp)
    ushort* xb   = Sb;                          // aliased (dead before scores)
    ushort* Wcat = Sb + BTC;

    dim3 blk(256);

    // 0) fp32 -> bf16 (single fused launch)
    cvt_all<<<dim3(5632), blk, 0, stream>>>(x, Wk, Wq, Wv, xb, Wcat);

    // 1) fused QKV projection (256x128, BK=32 ring-3, 2 blocks/CU)
    qkv_gemm256<<<dim3(768), dim3(512), 0, stream>>>(xb, Wcat, bk, bq, bv, Kb, Qb, Vt);

    // 2) scores -> P' = exp(s/32), causal (lower-triangle blocks; full diag tiles)
    gemm_ring<1><<<dim3(544), blk, 0, stream>>>(Kb, Qb, Vt, Sb, out);

    // 3) y = (P' @ V) / rowsum(P')  -- softmax normalization fused via ones-MFMA
    gemm_ring<2><<<dim3(512), blk, 0, stream>>>(Kb, Qb, Vt, Sb, out);
}